// Round 12
// baseline (79.703 us; speedup 1.0000x reference)
//
#include <hip/hip_runtime.h>

// Problem constants (fixed by setup_inputs)
#define B_   4
#define C_   256
#define H_   96
#define W_   128
#define F_   9
#define G_   4
#define CG   64            // channels per group
#define NC8  8             // channel OCTETS per group
#define NO   81            // offsets
#define HW_  (H_ * W_)

// Block: 512 threads = 8 out-rows x 64 cols (half width); 3 dy per pass
#define NDY   3
#define OROWS 8                  // output rows per block
#define TROWS 12                 // tap rows: r + 2*dyp, r=0..7, dyp=0..2 -> 0..11
#define TCOLS 80                 // 64 + 16 halo cols
#define PTE   (TROWS * TCOLS)    // 960 entries (16B: 8ch f16)
#define PNK   2                  // staging chunks 512 + 448

typedef _Float16 half2v __attribute__((ext_vector_type(2)));
typedef unsigned u32x4 __attribute__((ext_vector_type(4)));

__device__ __forceinline__ half2v u2h(unsigned u) {
    half2v h; __builtin_memcpy(&h, &u, 4); return h;
}
__device__ __forceinline__ unsigned h2u(half2v h) {
    unsigned u; __builtin_memcpy(&u, &h, 4); return u;
}
__device__ __forceinline__ half2v pkrtz(float a, float b) {
    auto r = __builtin_amdgcn_cvt_pkrtz(a, b);
    half2v h; __builtin_memcpy(&h, &r, 4); return h;
}
__device__ __forceinline__ unsigned pkrtz_u(float a, float b) {
    auto r = __builtin_amdgcn_cvt_pkrtz(a, b);
    unsigned u; __builtin_memcpy(&u, &r, 4); return u;
}

#if __has_builtin(__builtin_amdgcn_fdot2)
#define FDOT2(a, b, c) __builtin_amdgcn_fdot2((a), (b), (c), false)
#else
__device__ __forceinline__ float fdot2_fb(half2v a, half2v b, float c) {
    return c + (float)a[0] * (float)b[0] + (float)a[1] * (float)b[1];
}
#define FDOT2(a, b, c) fdot2_fb((a), (b), (c))
#endif

// Pack weights [C,9,9] f32 -> [g][c8][o] as 8-channel (4x f16x2) in d_ws
__global__ void pack_weights_kernel(const float* __restrict__ w,
                                    u32x4* __restrict__ wp) {
    int i = blockIdx.x * blockDim.x + threadIdx.x;
    if (i >= G_ * NC8 * NO) return;
    int o  = i % NO;
    int c8 = (i / NO) % NC8;
    int g  = i / (NO * NC8);
    const float* base = w + (size_t)(g * CG + 8 * c8) * NO + o;
    u32x4 r;
    r.x = pkrtz_u(base[0 * NO], base[1 * NO]);
    r.y = pkrtz_u(base[2 * NO], base[3 * NO]);
    r.z = pkrtz_u(base[4 * NO], base[5 * NO]);
    r.w = pkrtz_u(base[6 * NO], base[7 * NO]);
    wp[i] = r;
}

template <bool PACKED>
__global__ __launch_bounds__(512)
void wcorr_kernel(const float* __restrict__ in1, const float* __restrict__ in2,
                  const u32x4* __restrict__ wp, const float* __restrict__ wraw,
                  float* __restrict__ out) {
    __shared__ u32x4 tile[2][PTE];   // 30,720 B

    // grid = 1152: 16 pairs x {3 pass x 12 hblk x 2 half}
    // XCD-aware: (b,g) pair constant per XCD run -> in2 plane stays in XCD L2
    int bid  = blockIdx.x;
    int xcd  = bid & 7;
    int slot = bid >> 3;                 // 0..143
    int pair = xcd + 8 * (slot / 72);    // 0..15  == b*4+g
    int rem  = slot % 72;
    int pass = rem / 24;                 // 0..2  (dy block)
    int sub  = rem % 24;
    int hblk = sub >> 1;                 // 0..11
    int half = sub & 1;                  // col half
    int b = pair >> 2, g = pair & 3;
    int h0 = hblk * OROWS;
    int w0 = half * 64;

    int t = threadIdx.x;
    int r = t >> 6;                 // 0..7 output row (uniform per wave)
    int x = t & 63;                 // 0..63 output col within half

    const float* in1g = in1 + (size_t)(b * C_ + g * CG) * HW_;
    const float* in2g = in2 + (size_t)(b * C_ + g * CG) * HW_;

    // ---- staging geometry (c8-invariant): clamp + mask, branchless ----
    const int gr0 = h0 - 8 + 6 * pass;
    const int gc0 = w0 - 8;
    int po[PNK]; unsigned msk[PNK];
#pragma unroll
    for (int k = 0; k < PNK; ++k) {
        int pidx = k * 512 + t;
        int row  = pidx / TCOLS;
        int col  = pidx - row * TCOLS;
        int gr = gr0 + row, gc = gc0 + col;
        bool inb = (pidx < PTE) && gr >= 0 && gr < H_ && gc >= 0 && gc < W_;
        int off = gr * W_ + gc;
        off = off < 0 ? 0 : (off > HW_ - 1 ? HW_ - 1 : off);
        po[k]  = off;
        float m = inb ? 1.f : 0.f;
        msk[k] = pkrtz_u(m, m);
    }

    float acc[NDY * F_];
#pragma unroll
    for (int o = 0; o < NDY * F_; ++o) acc[o] = 0.f;

    // staged in2 values for ONE tile (8 ch x PNK chunks), live across compute
    float sv[PNK][8];

    auto LOADS = [&](int c8n) {
        const float* chb = in2g + (size_t)(8 * c8n) * HW_;
#pragma unroll
        for (int k = 0; k < PNK; ++k) {
            const float* q = chb + po[k];
#pragma unroll
            for (int j = 0; j < 8; ++j) sv[k][j] = q[(size_t)j * HW_];
        }
    };
    auto WRITE = [&](u32x4* dst) {
#pragma unroll
        for (int k = 0; k < PNK; ++k) {
            if (k < PNK - 1 || t < PTE - (PNK - 1) * 512) {
                half2v m = u2h(msk[k]);
                u32x4 e;
                e.x = h2u(u2h(pkrtz_u(sv[k][0], sv[k][1])) * m);
                e.y = h2u(u2h(pkrtz_u(sv[k][2], sv[k][3])) * m);
                e.z = h2u(u2h(pkrtz_u(sv[k][4], sv[k][5])) * m);
                e.w = h2u(u2h(pkrtz_u(sv[k][6], sv[k][7])) * m);
                dst[k * 512 + t] = e;    // ds_write_b128, contiguous
            }
        }
    };

    // ---- prologue: tile 0 staged; tile 1 loads in flight ----
    LOADS(0);
    WRITE(tile[0]);
    LOADS(1);

    const int in1off = (h0 + r) * W_ + (w0 + x);
    float a[8];
#pragma unroll
    for (int j = 0; j < 8; ++j) a[j] = in1g[in1off + (size_t)j * HW_];

    for (int c8 = 0; c8 < NC8; ++c8) {
        __syncthreads();   // tile[c8&1] readable; tile[(c8+1)&1] writable

        // write tile c8+1 (loads issued one FULL iteration ago -> vmcnt covered)
        if (c8 + 1 < NC8) WRITE(tile[(c8 + 1) & 1]);
        // issue loads for tile c8+2 (wait lands in NEXT iteration's WRITE)
        if (c8 + 2 < NC8) LOADS(c8 + 2);

        // pack current in1, then prefetch next octet into the same floats
        half2v ha0 = pkrtz(a[0], a[1]), ha1 = pkrtz(a[2], a[3]);
        half2v ha2 = pkrtz(a[4], a[5]), ha3 = pkrtz(a[6], a[7]);
        if (c8 + 1 < NC8) {
            const float* pp = in1g + (size_t)(8 * (c8 + 1)) * HW_ + in1off;
#pragma unroll
            for (int j = 0; j < 8; ++j) a[j] = pp[(size_t)j * HW_];
        }

        const u32x4* lt = tile[c8 & 1];
        const u32x4* wrow = PACKED ? (wp + ((size_t)g * NC8 + c8) * NO + pass * NDY * F_) : nullptr;
        const float* wr = wraw + (size_t)(g * CG + 8 * c8) * NO + pass * NDY * F_;

#pragma unroll
        for (int dyp = 0; dyp < NDY; ++dyp) {
            const u32x4* rowp = lt + (r + 2 * dyp) * TCOLS + x;
#pragma unroll
            for (int dx = 0; dx < F_; ++dx) {
                const int oo = dyp * F_ + dx;
                u32x4 uv = rowp[2 * dx];            // ds_read_b128, imm offset
                half2v w0h, w1h, w2h, w3h;
                if (PACKED) {
                    u32x4 wv = wrow[oo];            // block-uniform -> s_load x4
                    w0h = u2h(wv.x); w1h = u2h(wv.y);
                    w2h = u2h(wv.z); w3h = u2h(wv.w);
                } else {
                    w0h = pkrtz(wr[oo + 0 * NO], wr[oo + 1 * NO]);
                    w1h = pkrtz(wr[oo + 2 * NO], wr[oo + 3 * NO]);
                    w2h = pkrtz(wr[oo + 4 * NO], wr[oo + 5 * NO]);
                    w3h = pkrtz(wr[oo + 6 * NO], wr[oo + 7 * NO]);
                }
                float s = acc[oo];
                s = FDOT2(w0h * ha0, u2h(uv.x), s);
                s = FDOT2(w1h * ha1, u2h(uv.y), s);
                s = FDOT2(w2h * ha2, u2h(uv.z), s);
                s = FDOT2(w3h * ha3, u2h(uv.w), s);
                acc[oo] = s;
            }
        }
    }

    // out[b][g*81 + pass*27 + oo][h][w]
    size_t obase = (((size_t)pair * NO + pass * NDY * F_) * H_ + (h0 + r)) * W_ + (w0 + x);
#pragma unroll
    for (int oo = 0; oo < NDY * F_; ++oo)
        out[obase + (size_t)oo * HW_] = acc[oo];
}

extern "C" void kernel_launch(void* const* d_in, const int* in_sizes, int n_in,
                              void* d_out, int out_size, void* d_ws, size_t ws_size,
                              hipStream_t stream) {
    const float* in1  = (const float*)d_in[0];
    const float* in2  = (const float*)d_in[1];
    const float* wraw = (const float*)d_in[2];
    float* out = (float*)d_out;

    const size_t wp_bytes = (size_t)G_ * NC8 * NO * 16;  // 41,472 B
    const int nblocks = 16 * 3 * 12 * 2;                 // 1152

    if (ws_size >= wp_bytes) {
        u32x4* wp = (u32x4*)d_ws;
        int n = G_ * NC8 * NO;
        pack_weights_kernel<<<(n + 255) / 256, 256, 0, stream>>>(wraw, wp);
        wcorr_kernel<true><<<nblocks, 512, 0, stream>>>(in1, in2, wp, wraw, out);
    } else {
        wcorr_kernel<false><<<nblocks, 512, 0, stream>>>(in1, in2, nullptr, wraw, out);
    }
}